// Round 2
// baseline (591.917 us; speedup 1.0000x reference)
//
#include <hip/hip_runtime.h>
#include <hip/hip_bf16.h>
#include <math.h>

// ---------------------------------------------------------------------------
// WaveFormer on MI355X.  B=16, C=384, H=W=64, T=B*H*W=65536 tokens.
//   conv3x3 dw (NCHW, plane) -> pl2tok -> GEMM1(lin) -> xs PLANE + z token
//   GEMM2(tok, bf16 A) + fast gelu/cos/sin/decay epilogue -> mod, PLANE layout
//   spectral per (b,c) plane: Wn^T((Wn P Wn^T) .* M)Wn   (Wm==Wn since H==W)
//   pl2tok -> LN over C * silu(z) -> GEMM3(out) -> d_out fp32
// All 3 big GEMMs: m97-style 128x128 tile, BK=32, double-buffered LDS staged
// via global_load_lds width=16; XCD-aware 1D grid (row-blocks pinned per XCD,
// cols fastest) so A is HBM-fetched once and re-read from L2.
// LDS tile layout is K-OUTER [koff][row][8]: ds_read_b128 fragment loads are
// lane-contiguous 16B slots => zero bank conflicts (was 8-way at [row][32]).
// global_load_lds dest stays linear; only per-lane GLOBAL source is permuted.
// Workspace: 2 x 48MB ping-pong + ~1.2MB weights (~98MB). d_out (96MB) doubles
// as scratch for xs/z until GEMM3. freq bf16 reuses bufE's dead slot.
// ---------------------------------------------------------------------------

typedef __attribute__((ext_vector_type(8))) short short8;   // 8 bf16
typedef __attribute__((ext_vector_type(4))) float floatx4;

#define PIF 3.14159265358979323846f

__device__ __forceinline__ short f2bf(float f) {
    union { float f; unsigned u; } v; v.f = f;
    unsigned r = v.u + 0x7fffu + ((v.u >> 16) & 1u);   // RNE
    return (short)(r >> 16);
}
__device__ __forceinline__ float bf2f(short s) {
    union { unsigned u; float f; } v;
    v.u = ((unsigned)(unsigned short)s) << 16;
    return v.f;
}
// erf(x) via Abramowitz-Stegun 7.1.26 (max abs err 1.5e-7), fast __expf
__device__ __forceinline__ float fast_erf(float x) {
    float ax = fabsf(x);
    float t = 1.0f / fmaf(0.3275911f, ax, 1.0f);
    float poly = t * fmaf(t, fmaf(t, fmaf(t, fmaf(t, 1.061405429f, -1.453152027f),
                                          1.421413741f), -0.284496736f), 0.254829592f);
    float er = 1.0f - poly * __expf(-ax * ax);
    return copysignf(er, x);
}

// async global->LDS, 16B per lane. lds ptr must be wave-uniform base.
__device__ __forceinline__ void gload16(const short* g, short* l) {
    __builtin_amdgcn_global_load_lds(
        (const __attribute__((address_space(1))) void*)g,
        (__attribute__((address_space(3))) void*)l, 16, 0, 0);
}

// ---------------- fp32 -> bf16 bulk convert ----------------
__global__ __launch_bounds__(256) void k_f2bf(const float* __restrict__ src,
                                              short* __restrict__ dst, int n) {
    int i = (blockIdx.x * 256 + threadIdx.x) * 4;
    if (i < n) {
        float4 f = *(const float4*)(src + i);
        short4 o;
        o.x = f2bf(f.x); o.y = f2bf(f.y); o.z = f2bf(f.z); o.w = f2bf(f.w);
        *(short4*)(dst + i) = o;
    }
}

// ---------------- DCT basis (and transpose), bf16 ----------------
__global__ __launch_bounds__(256) void k_build_dct(short* __restrict__ wn,
                                                   short* __restrict__ wnt) {
    int i = blockIdx.x * 256 + threadIdx.x;
    if (i < 4096) {
        int n = i >> 6, h = i & 63;
        float v = cosf((float)n * ((float)h + 0.5f) * (PIF / 64.0f)) * sqrtf(2.0f / 64.0f);
        if (n == 0) v *= 0.70710678118654752f;
        short b = f2bf(v);
        wn[n * 64 + h]  = b;   // [n][h]
        wnt[h * 64 + n] = b;   // [h][n]
    }
}

// ---------------- depthwise 3x3 conv, NCHW fp32 -> NCHW bf16 ----------------
__global__ __launch_bounds__(256) void k_conv(const float* __restrict__ x,
                                              const float* __restrict__ w,
                                              const float* __restrict__ bias,
                                              short* __restrict__ out) {
    __shared__ float sp[4096];
    int bc = blockIdx.x;              // b*384 + c
    int c = bc % 384;
    int tid = threadIdx.x;
    const float* xp = x + (size_t)bc * 4096;
    for (int i = 0; i < 4; i++) {
        int e = i * 1024 + tid * 4;
        *(float4*)(sp + e) = *(const float4*)(xp + e);
    }
    float wt[9];
    #pragma unroll
    for (int j = 0; j < 9; j++) wt[j] = w[c * 9 + j];
    float bv = bias[c];
    __syncthreads();
    short* op = out + (size_t)bc * 4096;
    for (int i = 0; i < 16; i++) {
        int hw = i * 256 + tid;
        int h = hw >> 6, ww = hw & 63;
        float acc = bv;
        #pragma unroll
        for (int dh = 0; dh < 3; dh++) {
            int ih = h + dh - 1;
            if (ih < 0 || ih > 63) continue;
            #pragma unroll
            for (int dw = 0; dw < 3; dw++) {
                int iw = ww + dw - 1;
                if (iw < 0 || iw > 63) continue;
                acc += sp[ih * 64 + iw] * wt[dh * 3 + dw];
            }
        }
        op[hw] = f2bf(acc);
    }
}

// ---------------- plane [B][C][4096] -> token [T][384] ----------------
__global__ __launch_bounds__(256) void k_pl2tok(const short* __restrict__ src,
                                                short* __restrict__ dst) {
    __shared__ short tile[64 * 66];
    int ct = blockIdx.x, ht = blockIdx.y, b = blockIdx.z;
    int tid = threadIdx.x;
    const short* sp = src + ((size_t)b * 384 + ct * 64) * 4096 + ht * 64;
    for (int i = 0; i < 16; i++) {
        int idx = i * 256 + tid;
        int r = idx >> 6, col = idx & 63;              // r=c-local, col=hw-local
        tile[r * 66 + col] = sp[(size_t)r * 4096 + col];
    }
    __syncthreads();
    short* dp = dst + ((size_t)b * 4096 + ht * 64) * 384 + ct * 64;
    for (int i = 0; i < 16; i++) {
        int idx = i * 256 + tid;
        int r = idx >> 6, col = idx & 63;              // r=hw-local, col=c-local
        dp[(size_t)r * 384 + col] = tile[col * 66 + r];
    }
}

// ---------------------------------------------------------------------------
// Shared GEMM core: D-tile 128(M)x128(N), K=384, BK=32, 256 threads (4 waves,
// each 64x64 via 4x4 of 16x16x32). A [M][384] bf16 row-major, Bw [N][384] bf16
// row-major (both K-contiguous). Double-buffered LDS via global_load_lds w=16.
// K-outer LDS layout per tile: 16B slot q <- global chunk (row=q&127,
// koff=q>>7); fragment read addr = (quad*128 + row)*16B (lane-contiguous,
// conflict-free). smem: ldsA [2][512 slots] at 0, ldsB same at +8192 shorts.
// ---------------------------------------------------------------------------
__device__ __forceinline__ void mm_core(const short* __restrict__ A,
                                        const short* __restrict__ Bw,
                                        int row_base, int col_base,
                                        short* smem, floatx4 (&acc)[4][4]) {
    const int K = 384;
    int tid = threadIdx.x;
    int wid = tid >> 6, lane = tid & 63;
    int quad = lane >> 4, l16 = lane & 15;
    int rowh = (wid >> 1) * 64, colh = (wid & 1) * 64;
    short* ldsA = smem;
    short* ldsB = smem + 8192;
    const short* ga = A + (size_t)row_base * K;
    const short* gb = Bw + (size_t)col_base * K;

    // slot q holds (row=q&127, koff=q>>7); LDS dest stays linear in q.
    int q0 = tid, q1 = 256 + tid;
    int r0 = q0 & 127, o0 = (q0 >> 7) * 8;
    int r1 = q1 & 127, o1 = (q1 >> 7) * 8;
    short* la0 = ldsA + (wid * 64) * 8;          // wave-uniform dests
    short* la1 = ldsA + (256 + wid * 64) * 8;
    short* lb0 = ldsB + (wid * 64) * 8;
    short* lb1 = ldsB + (256 + wid * 64) * 8;

    auto stage = [&](int ks, int buf) {
        int k0 = ks * 32;
        gload16(ga + (size_t)r0 * K + k0 + o0, la0 + buf * 4096);
        gload16(ga + (size_t)r1 * K + k0 + o1, la1 + buf * 4096);
        gload16(gb + (size_t)r0 * K + k0 + o0, lb0 + buf * 4096);
        gload16(gb + (size_t)r1 * K + k0 + o1, lb1 + buf * 4096);
    };

    stage(0, 0);
    __syncthreads();
    #pragma unroll 2
    for (int ks = 0; ks < 12; ++ks) {
        int cur = ks & 1;
        if (ks < 11) stage(ks + 1, cur ^ 1);
        short8 af[4], bfr[4];
        #pragma unroll
        for (int s = 0; s < 4; s++) {
            af[s]  = *(const short8*)(ldsA + cur * 4096 + (quad * 128 + rowh + s * 16 + l16) * 8);
            bfr[s] = *(const short8*)(ldsB + cur * 4096 + (quad * 128 + colh + s * 16 + l16) * 8);
        }
        #pragma unroll
        for (int i = 0; i < 4; i++)
            #pragma unroll
            for (int j = 0; j < 4; j++)
                acc[i][j] = __builtin_amdgcn_mfma_f32_16x16x32_bf16(af[i], bfr[j], acc[i][j], 0, 0, 0);
        __syncthreads();   // drains vmcnt: next-buf staging complete + reads done
    }
}

// -------- GEMM1: D[M,768] = A[M,384]*lin_w^T + b; xs -> PLANE, z -> token ---
// grid 3072 1D: xcd = bid&7 owns row-blocks [xcd*64, +64), cols fastest.
__global__ __launch_bounds__(256) void k_gemm_split(const short* __restrict__ A,
                                                    const short* __restrict__ Bw,
                                                    const float* __restrict__ bias,
                                                    short* __restrict__ xs_pl,
                                                    short* __restrict__ z_tok) {
    __shared__ __align__(16) short smem[17408];  // staging 16384 | tile 128*136
    int bid = blockIdx.x;
    int xcd = bid & 7, local = bid >> 3;         // 384 blocks per XCD
    int bx = local % 6;
    int by = xcd * 64 + local / 6;
    int row_base = by * 128, col_base = bx * 128;
    int tid = threadIdx.x;
    int wid = tid >> 6, lane = tid & 63, quad = lane >> 4, l16 = lane & 15;
    int rowh = (wid >> 1) * 64, colh = (wid & 1) * 64;

    floatx4 zero = {0.f, 0.f, 0.f, 0.f};
    floatx4 acc[4][4];
    #pragma unroll
    for (int i = 0; i < 4; i++)
        #pragma unroll
        for (int j = 0; j < 4; j++) acc[i][j] = zero;

    mm_core(A, Bw, row_base, col_base, smem, acc);

    if (bx < 3) {
        // xs half: transpose through smem (staging dead), store plane layout
        #pragma unroll
        for (int i = 0; i < 4; i++)
            #pragma unroll
            for (int j = 0; j < 4; j++) {
                int cl = colh + j * 16 + l16;            // channel-local 0..127
                float bs = bias[col_base + cl];
                #pragma unroll
                for (int r = 0; r < 4; r++) {
                    int rl = rowh + i * 16 + quad * 4 + r;   // token-local 0..127
                    smem[cl * 136 + rl] = f2bf(acc[i][j][r] + bs);
                }
            }
        __syncthreads();
        int t0 = row_base;                 // 128 tokens, same b
        int b = t0 >> 12, hw0 = t0 & 4095;
        for (int it = 0; it < 8; it++) {
            int q = it * 256 + tid;
            int cl = q >> 4, t8 = (q & 15) * 8;
            short8 vv = *(const short8*)(smem + cl * 136 + t8);
            int c = col_base + cl;
            *(short8*)(xs_pl + ((size_t)b * 384 + c) * 4096 + hw0 + t8) = vv;
        }
    } else {
        // z half: token layout direct
        #pragma unroll
        for (int i = 0; i < 4; i++)
            #pragma unroll
            for (int j = 0; j < 4; j++) {
                int col = col_base + colh + j * 16 + l16;
                float bs = bias[col];
                int cc = col - 384;
                #pragma unroll
                for (int r = 0; r < 4; r++) {
                    int row = row_base + rowh + i * 16 + quad * 4 + r;
                    z_tok[(size_t)row * 384 + cc] = f2bf(acc[i][j][r] + bs);
                }
            }
    }
}

// -------- GEMM2: mod = f(gelu(freq @ tokw^T + b)), stored PLANE layout -----
__global__ __launch_bounds__(256) void k_gemm_mod(const short* __restrict__ A,
                                                  const short* __restrict__ Bw,
                                                  const float* __restrict__ bias,
                                                  short* __restrict__ Dpl,
                                                  const float* __restrict__ cp,
                                                  const float* __restrict__ ap) {
    __shared__ __align__(16) short smem[17408];
    int bid = blockIdx.x;
    int xcd = bid & 7, local = bid >> 3;         // 192 blocks per XCD
    int bx = local % 3;
    int by = xcd * 64 + local / 3;
    int row_base = by * 128, col_base = bx * 128;
    int tid = threadIdx.x;
    int wid = tid >> 6, lane = tid & 63, quad = lane >> 4, l16 = lane & 15;
    int rowh = (wid >> 1) * 64, colh = (wid & 1) * 64;

    floatx4 zero = {0.f, 0.f, 0.f, 0.f};
    floatx4 acc[4][4];
    #pragma unroll
    for (int i = 0; i < 4; i++)
        #pragma unroll
        for (int j = 0; j < 4; j++) acc[i][j] = zero;

    mm_core(A, Bw, row_base, col_base, smem, acc);

    float cv = cp[0], av = ap[0];
    float inv_c = 1.0f / (cv + 1e-8f);
    float gfac = 1.0f + 0.5f * av;
    #pragma unroll
    for (int i = 0; i < 4; i++) {
        #pragma unroll
        for (int j = 0; j < 4; j++) {
            int cl = colh + j * 16 + l16;
            float bs = bias[col_base + cl];
            #pragma unroll
            for (int r = 0; r < 4; r++) {
                int rl = rowh + i * 16 + quad * 4 + r;
                int row = row_base + rl;
                float v = acc[i][j][r] + bs;
                float t = 0.5f * v * (1.0f + fast_erf(v * 0.70710678118654752f));
                float ct = cv * t;
                float sn, cs;
                __sincosf(ct, &sn, &cs);
                float fac = cs + sn * inv_c * gfac;
                int nn = (row >> 6) & 63, mm = row & 63;
                float wnf = (float)nn * (PIF / 64.0f);
                float wmf = (float)mm * (PIF / 64.0f);
                float mod = fac * __expf(-(wnf * wnf + wmf * wmf) * t);
                smem[cl * 136 + rl] = f2bf(mod);
            }
        }
    }
    __syncthreads();
    // coalesced plane store: 128 tokens (same b) x 128 channels
    int t0 = row_base;
    int b = t0 >> 12, hw0 = t0 & 4095;
    for (int it = 0; it < 8; it++) {
        int q = it * 256 + tid;
        int cl = q >> 4, t8 = (q & 15) * 8;
        short8 vv = *(const short8*)(smem + cl * 136 + t8);
        int c = col_base + cl;
        *(short8*)(Dpl + ((size_t)b * 384 + c) * 4096 + hw0 + t8) = vv;
    }
}

// ---------------- spectral: per (b,c) plane, 4 chained 64x64x64 MFMA GEMMs ----
// xo = Wn^T ((Wn P Wn^T) .* M) Wn
__global__ __launch_bounds__(256) void k_spectral(const short* __restrict__ xs,   // [B][C][4096] [h][w]
                                                  const short* __restrict__ mod,  // [B][C][4096] [n][m]
                                                  const short* __restrict__ wn,   // [n][h]
                                                  const short* __restrict__ wnt,  // [h][n]
                                                  short* __restrict__ xo) {       // [B][C][4096]
    __shared__ short sWn[4096], sWt[4096], sP[4096], sM[4096], sT[4096];
    int bc = blockIdx.x;
    int tid = threadIdx.x;
    int wid = tid >> 6, lane = tid & 63, quad = lane >> 4, l16 = lane & 15;
    const short* xp = xs + (size_t)bc * 4096;
    const short* mp = mod + (size_t)bc * 4096;
    floatx4 zero = {0.f, 0.f, 0.f, 0.f};

    for (int i = 0; i < 2; i++) {
        int e = i * 2048 + tid * 8;
        *(short8*)(sWn + e) = *(const short8*)(wn + e);
        *(short8*)(sWt + e) = *(const short8*)(wnt + e);
        *(short8*)(sM + e)  = *(const short8*)(mp + e);
        short8 pv = *(const short8*)(xp + e);
        int h = e >> 6, w0 = e & 63;
        #pragma unroll
        for (int j = 0; j < 8; j++) sP[(w0 + j) * 64 + h] = pv[j];   // sP = P^T [w][h]
    }
    __syncthreads();

    int mrow = wid * 16;   // this wave's 16 output rows at every stage
    floatx4 acc[4];

    // S1: T1[n][w] = sum_h Wn[n][h] P[h][w];  A=sWn rows, B reads sP[w][h]
    #pragma unroll
    for (int j = 0; j < 4; j++) acc[j] = zero;
    #pragma unroll
    for (int ks = 0; ks < 2; ks++) {
        int k0 = ks * 32 + quad * 8;
        short8 a = *(const short8*)(sWn + (mrow + l16) * 64 + k0);
        #pragma unroll
        for (int j = 0; j < 4; j++) {
            short8 b = *(const short8*)(sP + (j * 16 + l16) * 64 + k0);
            acc[j] = __builtin_amdgcn_mfma_f32_16x16x32_bf16(a, b, acc[j], 0, 0, 0);
        }
    }
    #pragma unroll
    for (int j = 0; j < 4; j++)
        #pragma unroll
        for (int r = 0; r < 4; r++)
            sT[(mrow + quad * 4 + r) * 64 + j * 16 + l16] = f2bf(acc[j][r]);  // sT = T1 [n][w]
    __syncthreads();

    // S2: T2[n][m] = sum_w T1[n][w] Wn[m][w];  A=sT rows, B reads sWn[m][w]
    #pragma unroll
    for (int j = 0; j < 4; j++) acc[j] = zero;
    #pragma unroll
    for (int ks = 0; ks < 2; ks++) {
        int k0 = ks * 32 + quad * 8;
        short8 a = *(const short8*)(sT + (mrow + l16) * 64 + k0);
        #pragma unroll
        for (int j = 0; j < 4; j++) {
            short8 b = *(const short8*)(sWn + (j * 16 + l16) * 64 + k0);
            acc[j] = __builtin_amdgcn_mfma_f32_16x16x32_bf16(a, b, acc[j], 0, 0, 0);
        }
    }
    __syncthreads();
    // epilogue: multiply Mod, store transposed into sP as [m][n]
    #pragma unroll
    for (int j = 0; j < 4; j++)
        #pragma unroll
        for (int r = 0; r < 4; r++) {
            int n = mrow + quad * 4 + r, m = j * 16 + l16;
            float v = acc[j][r] * bf2f(sM[n * 64 + m]);
            sP[m * 64 + n] = f2bf(v);
        }
    __syncthreads();

    // S3: T3[h][m] = sum_n WnT[h][n] T2'[n][m];  A=sWt rows, B reads sP[m][n]
    #pragma unroll
    for (int j = 0; j < 4; j++) acc[j] = zero;
    #pragma unroll
    for (int ks = 0; ks < 2; ks++) {
        int k0 = ks * 32 + quad * 8;
        short8 a = *(const short8*)(sWt + (mrow + l16) * 64 + k0);
        #pragma unroll
        for (int j = 0; j < 4; j++) {
            short8 b = *(const short8*)(sP + (j * 16 + l16) * 64 + k0);
            acc[j] = __builtin_amdgcn_mfma_f32_16x16x32_bf16(a, b, acc[j], 0, 0, 0);
        }
    }
    __syncthreads();
    #pragma unroll
    for (int j = 0; j < 4; j++)
        #pragma unroll
        for (int r = 0; r < 4; r++)
            sT[(mrow + quad * 4 + r) * 64 + j * 16 + l16] = f2bf(acc[j][r]);  // sT = T3 [h][m]
    __syncthreads();

    // S4: XO[h][w] = sum_m T3[h][m] Wn[m][w];  A=sT rows, B reads sWt[w][m]
    #pragma unroll
    for (int j = 0; j < 4; j++) acc[j] = zero;
    #pragma unroll
    for (int ks = 0; ks < 2; ks++) {
        int k0 = ks * 32 + quad * 8;
        short8 a = *(const short8*)(sT + (mrow + l16) * 64 + k0);
        #pragma unroll
        for (int j = 0; j < 4; j++) {
            short8 b = *(const short8*)(sWt + (j * 16 + l16) * 64 + k0);
            acc[j] = __builtin_amdgcn_mfma_f32_16x16x32_bf16(a, b, acc[j], 0, 0, 0);
        }
    }
    short* op = xo + (size_t)bc * 4096;
    #pragma unroll
    for (int j = 0; j < 4; j++)
        #pragma unroll
        for (int r = 0; r < 4; r++) {
            int h = mrow + quad * 4 + r, w = j * 16 + l16;
            op[h * 64 + w] = f2bf(acc[j][r]);
        }
}

// ---------------- layernorm over C, * silu(z) ----------------
__global__ __launch_bounds__(256) void k_ln_silu(const short* __restrict__ xo,  // [T][384]
                                                 const short* __restrict__ z,   // [T][384]
                                                 const float* __restrict__ g,
                                                 const float* __restrict__ bb,
                                                 short* __restrict__ y) {
    int wid = threadIdx.x >> 6, lane = threadIdx.x & 63;
    size_t token = (size_t)blockIdx.x * 4 + wid;
    const short* xp = xo + token * 384;
    float v[6];
    float s = 0.f, sq = 0.f;
    #pragma unroll
    for (int j = 0; j < 6; j++) {
        v[j] = bf2f(xp[lane + j * 64]);
        s += v[j]; sq += v[j] * v[j];
    }
    #pragma unroll
    for (int m = 1; m < 64; m <<= 1) {
        s  += __shfl_xor(s, m, 64);
        sq += __shfl_xor(sq, m, 64);
    }
    float mu = s * (1.0f / 384.0f);
    float var = sq * (1.0f / 384.0f) - mu * mu;
    float rstd = rsqrtf(var + 1e-5f);
    const short* zp = z + token * 384;
    short* yp = y + token * 384;
    #pragma unroll
    for (int j = 0; j < 6; j++) {
        int cc = lane + j * 64;
        float zz = bf2f(zp[cc]);
        float sil = zz / (1.f + __expf(-zz));
        float o = (v[j] - mu) * rstd * g[cc] + bb[cc];
        yp[cc] = f2bf(o * sil);
    }
}

// -------- GEMM3: out[M,384] = Y[M,384] * out_w^T + bias, fp32 store ---------
__global__ __launch_bounds__(256) void k_gemm_f32out(const short* __restrict__ A,
                                                     const short* __restrict__ Bw,
                                                     const float* __restrict__ bias,
                                                     float* __restrict__ D) {
    __shared__ __align__(16) short smem[17408];
    const int N = 384;
    int bid = blockIdx.x;
    int xcd = bid & 7, local = bid >> 3;
    int bx = local % 3;
    int by = xcd * 64 + local / 3;
    int row_base = by * 128, col_base = bx * 128;
    int tid = threadIdx.x;
    int wid = tid >> 6, lane = tid & 63, quad = lane >> 4, l16 = lane & 15;
    int rowh = (wid >> 1) * 64, colh = (wid & 1) * 64;

    floatx4 zero = {0.f, 0.f, 0.f, 0.f};
    floatx4 acc[4][4];
    #pragma unroll
    for (int i = 0; i < 4; i++)
        #pragma unroll
        for (int j = 0; j < 4; j++) acc[i][j] = zero;

    mm_core(A, Bw, row_base, col_base, smem, acc);

    #pragma unroll
    for (int i = 0; i < 4; i++) {
        #pragma unroll
        for (int j = 0; j < 4; j++) {
            int col = col_base + colh + j * 16 + l16;
            float bs = bias[col];
            #pragma unroll
            for (int r = 0; r < 4; r++) {
                int row = row_base + rowh + i * 16 + quad * 4 + r;
                D[(size_t)row * N + col] = acc[i][j][r] + bs;
            }
        }
    }
}

// ---------------------------------------------------------------------------
extern "C" void kernel_launch(void* const* d_in, const int* in_sizes, int n_in,
                              void* d_out, int out_size, void* d_ws, size_t ws_size,
                              hipStream_t stream) {
    const float* x     = (const float*)d_in[0];
    const float* freq  = (const float*)d_in[1];
    const float* dw_w  = (const float*)d_in[2];
    const float* dw_b  = (const float*)d_in[3];
    const float* lin_w = (const float*)d_in[4];
    const float* lin_b = (const float*)d_in[5];
    const float* tok_w = (const float*)d_in[6];
    const float* tok_b = (const float*)d_in[7];
    const float* ln_g  = (const float*)d_in[8];
    const float* ln_b  = (const float*)d_in[9];
    const float* out_w = (const float*)d_in[10];
    const float* out_b = (const float*)d_in[11];
    const float* cp    = (const float*)d_in[12];
    const float* ap    = (const float*)d_in[13];
    float* out = (float*)d_out;
    (void)in_sizes; (void)n_in; (void)ws_size;

    // d_out (96MiB fp32) doubles as two 48MiB bf16 scratch tensors until GEMM3.
    const size_t TC = (size_t)65536 * 384;   // 25165824
    short* bufA = (short*)d_out;             // xs plane -> xo token
    short* bufB = (short*)d_out + TC;        // z token (alive until ln_silu)

    char* ws = (char*)d_ws;
    size_t off = 0;
    auto alloc = [&](size_t bytes) {
        char* p = ws + off; off += (bytes + 255) & ~(size_t)255; return p;
    };
    short* wn_bf   = (short*)alloc(4096 * 2);
    short* wnt_bf  = (short*)alloc(4096 * 2);
    short* linw_bf = (short*)alloc((size_t)294912 * 2);
    short* tokw_bf = (short*)alloc((size_t)147456 * 2);
    short* outw_bf = (short*)alloc((size_t)147456 * 2);
    short* bufC    = (short*)alloc(TC * 2);  // xd token -> mod plane -> y token
    short* bufE    = (short*)alloc(TC * 2);  // xd plane -> freq bf16 -> xo plane
    // total ws: ~98.3 MB

    k_f2bf<<<288, 256, 0, stream>>>(lin_w, linw_bf, 294912);
    k_f2bf<<<144, 256, 0, stream>>>(tok_w, tokw_bf, 147456);
    k_f2bf<<<144, 256, 0, stream>>>(out_w, outw_bf, 147456);
    k_build_dct<<<16, 256, 0, stream>>>(wn_bf, wnt_bf);

    k_conv<<<6144, 256, 0, stream>>>(x, dw_w, dw_b, bufE);            // xd plane
    k_pl2tok<<<dim3(6, 64, 16), 256, 0, stream>>>(bufE, bufC);        // xd token
    k_gemm_split<<<3072, 256, 0, stream>>>(bufC, linw_bf, lin_b,
                                           bufA, bufB);               // xs PLANE, z token
    k_f2bf<<<24576, 256, 0, stream>>>(freq, bufE, 25165824);          // freq bf16 (xd plane dead)
    k_gemm_mod<<<1536, 256, 0, stream>>>(bufE, tokw_bf, tok_b,
                                         bufC, cp, ap);               // mod plane (xd tok dead)
    k_spectral<<<6144, 256, 0, stream>>>(bufA, bufC, wn_bf, wnt_bf,
                                         bufE);                       // xo plane (freq bf dead)
    k_pl2tok<<<dim3(6, 64, 16), 256, 0, stream>>>(bufE, bufA);        // xo token (xs plane dead)
    k_ln_silu<<<16384, 256, 0, stream>>>(bufA, bufB, ln_g, ln_b, bufC); // y token (mod dead)
    k_gemm_f32out<<<1536, 256, 0, stream>>>(bufC, outw_bf, out_b, out);
}

// Round 3
// 544.946 us; speedup vs baseline: 1.0862x; 1.0862x over previous
//
#include <hip/hip_runtime.h>
#include <hip/hip_bf16.h>
#include <math.h>

// ---------------------------------------------------------------------------
// WaveFormer on MI355X.  B=16, C=384, H=W=64, T=B*H*W=65536 tokens.
//   conv3x3 dw (NCHW, plane) -> pl2tok -> GEMM1(lin) -> xs PLANE + z token
//   GEMM2(tok, bf16 A) + fast gelu/cos/sin/decay epilogue -> mod, PLANE layout
//   spectral per (b,c) plane: Wn^T((Wn P Wn^T) .* M)Wn   (Wm==Wn since H==W)
//   pl2tok -> LN over C * silu(z) -> GEMM3(out) -> d_out fp32
// All 3 big GEMMs: m97-style 128x128 tile, BK=32, double-buffered LDS staged
// via global_load_lds width=16; XCD-aware 1D grid (row-blocks pinned per XCD,
// cols fastest) so A is HBM-fetched once and re-read from L2.
// LDS tile: XOR-swizzled round-1 layout. Slot q <- chunk (row=q>>2,
// koff=(q&3)^((q>>3)&3)). Staging quarter-waves still cover whole 64B rows
// (global coalescing preserved: the per-wave ADDRESS SET is unchanged, only
// the lane->chunk assignment), and fragment ds_read_b128 hits each bank
// exactly 2x per 16-lane group => conflict-free (2-way is free, m136).
// global_load_lds dest stays linear; source permutation == read permutation.
// Workspace: 2 x 48MB ping-pong + ~1.2MB weights (~98MB). d_out (96MB) doubles
// as scratch for xs/z until GEMM3. freq bf16 reuses bufE's dead slot.
// ---------------------------------------------------------------------------

typedef __attribute__((ext_vector_type(8))) short short8;   // 8 bf16
typedef __attribute__((ext_vector_type(4))) float floatx4;

#define PIF 3.14159265358979323846f

__device__ __forceinline__ short f2bf(float f) {
    union { float f; unsigned u; } v; v.f = f;
    unsigned r = v.u + 0x7fffu + ((v.u >> 16) & 1u);   // RNE
    return (short)(r >> 16);
}
__device__ __forceinline__ float bf2f(short s) {
    union { unsigned u; float f; } v;
    v.u = ((unsigned)(unsigned short)s) << 16;
    return v.f;
}
// erf(x) via Abramowitz-Stegun 7.1.26 (max abs err 1.5e-7), fast __expf
__device__ __forceinline__ float fast_erf(float x) {
    float ax = fabsf(x);
    float t = 1.0f / fmaf(0.3275911f, ax, 1.0f);
    float poly = t * fmaf(t, fmaf(t, fmaf(t, fmaf(t, 1.061405429f, -1.453152027f),
                                          1.421413741f), -0.284496736f), 0.254829592f);
    float er = 1.0f - poly * __expf(-ax * ax);
    return copysignf(er, x);
}

// async global->LDS, 16B per lane. lds ptr must be wave-uniform base.
__device__ __forceinline__ void gload16(const short* g, short* l) {
    __builtin_amdgcn_global_load_lds(
        (const __attribute__((address_space(1))) void*)g,
        (__attribute__((address_space(3))) void*)l, 16, 0, 0);
}

// ---------------- fp32 -> bf16 bulk convert ----------------
__global__ __launch_bounds__(256) void k_f2bf(const float* __restrict__ src,
                                              short* __restrict__ dst, int n) {
    int i = (blockIdx.x * 256 + threadIdx.x) * 4;
    if (i < n) {
        float4 f = *(const float4*)(src + i);
        short4 o;
        o.x = f2bf(f.x); o.y = f2bf(f.y); o.z = f2bf(f.z); o.w = f2bf(f.w);
        *(short4*)(dst + i) = o;
    }
}

// ---------------- DCT basis (and transpose), bf16 ----------------
__global__ __launch_bounds__(256) void k_build_dct(short* __restrict__ wn,
                                                   short* __restrict__ wnt) {
    int i = blockIdx.x * 256 + threadIdx.x;
    if (i < 4096) {
        int n = i >> 6, h = i & 63;
        float v = cosf((float)n * ((float)h + 0.5f) * (PIF / 64.0f)) * sqrtf(2.0f / 64.0f);
        if (n == 0) v *= 0.70710678118654752f;
        short b = f2bf(v);
        wn[n * 64 + h]  = b;   // [n][h]
        wnt[h * 64 + n] = b;   // [h][n]
    }
}

// ---------------- depthwise 3x3 conv, NCHW fp32 -> NCHW bf16 ----------------
__global__ __launch_bounds__(256) void k_conv(const float* __restrict__ x,
                                              const float* __restrict__ w,
                                              const float* __restrict__ bias,
                                              short* __restrict__ out) {
    __shared__ float sp[4096];
    int bc = blockIdx.x;              // b*384 + c
    int c = bc % 384;
    int tid = threadIdx.x;
    const float* xp = x + (size_t)bc * 4096;
    for (int i = 0; i < 4; i++) {
        int e = i * 1024 + tid * 4;
        *(float4*)(sp + e) = *(const float4*)(xp + e);
    }
    float wt[9];
    #pragma unroll
    for (int j = 0; j < 9; j++) wt[j] = w[c * 9 + j];
    float bv = bias[c];
    __syncthreads();
    short* op = out + (size_t)bc * 4096;
    for (int i = 0; i < 16; i++) {
        int hw = i * 256 + tid;
        int h = hw >> 6, ww = hw & 63;
        float acc = bv;
        #pragma unroll
        for (int dh = 0; dh < 3; dh++) {
            int ih = h + dh - 1;
            if (ih < 0 || ih > 63) continue;
            #pragma unroll
            for (int dw = 0; dw < 3; dw++) {
                int iw = ww + dw - 1;
                if (iw < 0 || iw > 63) continue;
                acc += sp[ih * 64 + iw] * wt[dh * 3 + dw];
            }
        }
        op[hw] = f2bf(acc);
    }
}

// ---------------- plane [B][C][4096] -> token [T][384] ----------------
__global__ __launch_bounds__(256) void k_pl2tok(const short* __restrict__ src,
                                                short* __restrict__ dst) {
    __shared__ short tile[64 * 66];
    int ct = blockIdx.x, ht = blockIdx.y, b = blockIdx.z;
    int tid = threadIdx.x;
    const short* sp = src + ((size_t)b * 384 + ct * 64) * 4096 + ht * 64;
    for (int i = 0; i < 16; i++) {
        int idx = i * 256 + tid;
        int r = idx >> 6, col = idx & 63;              // r=c-local, col=hw-local
        tile[r * 66 + col] = sp[(size_t)r * 4096 + col];
    }
    __syncthreads();
    short* dp = dst + ((size_t)b * 4096 + ht * 64) * 384 + ct * 64;
    for (int i = 0; i < 16; i++) {
        int idx = i * 256 + tid;
        int r = idx >> 6, col = idx & 63;              // r=hw-local, col=c-local
        dp[(size_t)r * 384 + col] = tile[col * 66 + r];
    }
}

// ---------------------------------------------------------------------------
// Shared GEMM core: D-tile 128(M)x128(N), K=384, BK=32, 256 threads (4 waves,
// each 64x64 via 4x4 of 16x16x32). A [M][384] bf16 row-major, Bw [N][384] bf16
// row-major (both K-contiguous). Double-buffered LDS via global_load_lds w=16.
// XOR-swizzled tile: 16B slot q holds chunk (row=q>>2, koff=(q&3)^((q>>3)&3)).
//  - staging: lane reads global (row, koff(q)) -> quarter-wave covers 4 full
//    64B rows (coalesced, round-1 pattern).
//  - fragment read: slot = row*4 + (quad ^ ((l16>>1)&3)) -> each bank hit 2x
//    per 16-lane group => conflict-free.
// smem: ldsA [2][512 slots] at 0, ldsB same at +8192 shorts.
// ---------------------------------------------------------------------------
__device__ __forceinline__ void mm_core(const short* __restrict__ A,
                                        const short* __restrict__ Bw,
                                        int row_base, int col_base,
                                        short* smem, floatx4 (&acc)[4][4]) {
    const int K = 384;
    int tid = threadIdx.x;
    int wid = tid >> 6, lane = tid & 63;
    int quad = lane >> 4, l16 = lane & 15;
    int rowh = (wid >> 1) * 64, colh = (wid & 1) * 64;
    short* ldsA = smem;
    short* ldsB = smem + 8192;
    const short* ga = A + (size_t)row_base * K;
    const short* gb = Bw + (size_t)col_base * K;

    // slot q holds (row=q>>2, koff=(q&3)^((q>>3)&3)); LDS dest linear in q.
    int q0 = tid, q1 = 256 + tid;
    int r0 = q0 >> 2, o0 = ((q0 & 3) ^ ((q0 >> 3) & 3)) * 8;
    int r1 = q1 >> 2, o1 = ((q1 & 3) ^ ((q1 >> 3) & 3)) * 8;
    short* la0 = ldsA + (wid * 64) * 8;          // wave-uniform dests
    short* la1 = ldsA + (256 + wid * 64) * 8;
    short* lb0 = ldsB + (wid * 64) * 8;
    short* lb1 = ldsB + (256 + wid * 64) * 8;

    auto stage = [&](int ks, int buf) {
        int k0 = ks * 32;
        gload16(ga + (size_t)r0 * K + k0 + o0, la0 + buf * 4096);
        gload16(ga + (size_t)r1 * K + k0 + o1, la1 + buf * 4096);
        gload16(gb + (size_t)r0 * K + k0 + o0, lb0 + buf * 4096);
        gload16(gb + (size_t)r1 * K + k0 + o1, lb1 + buf * 4096);
    };

    int ksw = (quad ^ ((l16 >> 1) & 3)) * 8;     // per-lane swizzled k-slot

    stage(0, 0);
    __syncthreads();
    #pragma unroll 2
    for (int ks = 0; ks < 12; ++ks) {
        int cur = ks & 1;
        if (ks < 11) stage(ks + 1, cur ^ 1);
        short8 af[4], bfr[4];
        #pragma unroll
        for (int s = 0; s < 4; s++) {
            af[s]  = *(const short8*)(ldsA + cur * 4096 + (rowh + s * 16 + l16) * 32 + ksw);
            bfr[s] = *(const short8*)(ldsB + cur * 4096 + (colh + s * 16 + l16) * 32 + ksw);
        }
        #pragma unroll
        for (int i = 0; i < 4; i++)
            #pragma unroll
            for (int j = 0; j < 4; j++)
                acc[i][j] = __builtin_amdgcn_mfma_f32_16x16x32_bf16(af[i], bfr[j], acc[i][j], 0, 0, 0);
        __syncthreads();   // drains vmcnt: next-buf staging complete + reads done
    }
}

// -------- GEMM1: D[M,768] = A[M,384]*lin_w^T + b; xs -> PLANE, z -> token ---
// grid 3072 1D: xcd = bid&7 owns row-blocks [xcd*64, +64), cols fastest.
__global__ __launch_bounds__(256) void k_gemm_split(const short* __restrict__ A,
                                                    const short* __restrict__ Bw,
                                                    const float* __restrict__ bias,
                                                    short* __restrict__ xs_pl,
                                                    short* __restrict__ z_tok) {
    __shared__ __align__(16) short smem[17408];  // staging 16384 | tile 128*136
    int bid = blockIdx.x;
    int xcd = bid & 7, local = bid >> 3;         // 384 blocks per XCD
    int bx = local % 6;
    int by = xcd * 64 + local / 6;
    int row_base = by * 128, col_base = bx * 128;
    int tid = threadIdx.x;
    int wid = tid >> 6, lane = tid & 63, quad = lane >> 4, l16 = lane & 15;
    int rowh = (wid >> 1) * 64, colh = (wid & 1) * 64;

    floatx4 zero = {0.f, 0.f, 0.f, 0.f};
    floatx4 acc[4][4];
    #pragma unroll
    for (int i = 0; i < 4; i++)
        #pragma unroll
        for (int j = 0; j < 4; j++) acc[i][j] = zero;

    mm_core(A, Bw, row_base, col_base, smem, acc);

    if (bx < 3) {
        // xs half: transpose through smem (staging dead), store plane layout
        #pragma unroll
        for (int i = 0; i < 4; i++)
            #pragma unroll
            for (int j = 0; j < 4; j++) {
                int cl = colh + j * 16 + l16;            // channel-local 0..127
                float bs = bias[col_base + cl];
                #pragma unroll
                for (int r = 0; r < 4; r++) {
                    int rl = rowh + i * 16 + quad * 4 + r;   // token-local 0..127
                    smem[cl * 136 + rl] = f2bf(acc[i][j][r] + bs);
                }
            }
        __syncthreads();
        int t0 = row_base;                 // 128 tokens, same b
        int b = t0 >> 12, hw0 = t0 & 4095;
        for (int it = 0; it < 8; it++) {
            int q = it * 256 + tid;
            int cl = q >> 4, t8 = (q & 15) * 8;
            short8 vv = *(const short8*)(smem + cl * 136 + t8);
            int c = col_base + cl;
            *(short8*)(xs_pl + ((size_t)b * 384 + c) * 4096 + hw0 + t8) = vv;
        }
    } else {
        // z half: token layout direct
        #pragma unroll
        for (int i = 0; i < 4; i++)
            #pragma unroll
            for (int j = 0; j < 4; j++) {
                int col = col_base + colh + j * 16 + l16;
                float bs = bias[col];
                int cc = col - 384;
                #pragma unroll
                for (int r = 0; r < 4; r++) {
                    int row = row_base + rowh + i * 16 + quad * 4 + r;
                    z_tok[(size_t)row * 384 + cc] = f2bf(acc[i][j][r] + bs);
                }
            }
    }
}

// -------- GEMM2: mod = f(gelu(freq @ tokw^T + b)), stored PLANE layout -----
__global__ __launch_bounds__(256) void k_gemm_mod(const short* __restrict__ A,
                                                  const short* __restrict__ Bw,
                                                  const float* __restrict__ bias,
                                                  short* __restrict__ Dpl,
                                                  const float* __restrict__ cp,
                                                  const float* __restrict__ ap) {
    __shared__ __align__(16) short smem[17408];
    int bid = blockIdx.x;
    int xcd = bid & 7, local = bid >> 3;         // 192 blocks per XCD
    int bx = local % 3;
    int by = xcd * 64 + local / 3;
    int row_base = by * 128, col_base = bx * 128;
    int tid = threadIdx.x;
    int wid = tid >> 6, lane = tid & 63, quad = lane >> 4, l16 = lane & 15;
    int rowh = (wid >> 1) * 64, colh = (wid & 1) * 64;

    floatx4 zero = {0.f, 0.f, 0.f, 0.f};
    floatx4 acc[4][4];
    #pragma unroll
    for (int i = 0; i < 4; i++)
        #pragma unroll
        for (int j = 0; j < 4; j++) acc[i][j] = zero;

    mm_core(A, Bw, row_base, col_base, smem, acc);

    float cv = cp[0], av = ap[0];
    float inv_c = 1.0f / (cv + 1e-8f);
    float gfac = 1.0f + 0.5f * av;
    #pragma unroll
    for (int i = 0; i < 4; i++) {
        #pragma unroll
        for (int j = 0; j < 4; j++) {
            int cl = colh + j * 16 + l16;
            float bs = bias[col_base + cl];
            #pragma unroll
            for (int r = 0; r < 4; r++) {
                int rl = rowh + i * 16 + quad * 4 + r;
                int row = row_base + rl;
                float v = acc[i][j][r] + bs;
                float t = 0.5f * v * (1.0f + fast_erf(v * 0.70710678118654752f));
                float ct = cv * t;
                float sn, cs;
                __sincosf(ct, &sn, &cs);
                float fac = cs + sn * inv_c * gfac;
                int nn = (row >> 6) & 63, mm = row & 63;
                float wnf = (float)nn * (PIF / 64.0f);
                float wmf = (float)mm * (PIF / 64.0f);
                float mod = fac * __expf(-(wnf * wnf + wmf * wmf) * t);
                smem[cl * 136 + rl] = f2bf(mod);
            }
        }
    }
    __syncthreads();
    // coalesced plane store: 128 tokens (same b) x 128 channels
    int t0 = row_base;
    int b = t0 >> 12, hw0 = t0 & 4095;
    for (int it = 0; it < 8; it++) {
        int q = it * 256 + tid;
        int cl = q >> 4, t8 = (q & 15) * 8;
        short8 vv = *(const short8*)(smem + cl * 136 + t8);
        int c = col_base + cl;
        *(short8*)(Dpl + ((size_t)b * 384 + c) * 4096 + hw0 + t8) = vv;
    }
}

// ---------------- spectral: per (b,c) plane, 4 chained 64x64x64 MFMA GEMMs ----
// xo = Wn^T ((Wn P Wn^T) .* M) Wn
__global__ __launch_bounds__(256) void k_spectral(const short* __restrict__ xs,   // [B][C][4096] [h][w]
                                                  const short* __restrict__ mod,  // [B][C][4096] [n][m]
                                                  const short* __restrict__ wn,   // [n][h]
                                                  const short* __restrict__ wnt,  // [h][n]
                                                  short* __restrict__ xo) {       // [B][C][4096]
    __shared__ short sWn[4096], sWt[4096], sP[4096], sM[4096], sT[4096];
    int bc = blockIdx.x;
    int tid = threadIdx.x;
    int wid = tid >> 6, lane = tid & 63, quad = lane >> 4, l16 = lane & 15;
    const short* xp = xs + (size_t)bc * 4096;
    const short* mp = mod + (size_t)bc * 4096;
    floatx4 zero = {0.f, 0.f, 0.f, 0.f};

    for (int i = 0; i < 2; i++) {
        int e = i * 2048 + tid * 8;
        *(short8*)(sWn + e) = *(const short8*)(wn + e);
        *(short8*)(sWt + e) = *(const short8*)(wnt + e);
        *(short8*)(sM + e)  = *(const short8*)(mp + e);
        short8 pv = *(const short8*)(xp + e);
        int h = e >> 6, w0 = e & 63;
        #pragma unroll
        for (int j = 0; j < 8; j++) sP[(w0 + j) * 64 + h] = pv[j];   // sP = P^T [w][h]
    }
    __syncthreads();

    int mrow = wid * 16;   // this wave's 16 output rows at every stage
    floatx4 acc[4];

    // S1: T1[n][w] = sum_h Wn[n][h] P[h][w];  A=sWn rows, B reads sP[w][h]
    #pragma unroll
    for (int j = 0; j < 4; j++) acc[j] = zero;
    #pragma unroll
    for (int ks = 0; ks < 2; ks++) {
        int k0 = ks * 32 + quad * 8;
        short8 a = *(const short8*)(sWn + (mrow + l16) * 64 + k0);
        #pragma unroll
        for (int j = 0; j < 4; j++) {
            short8 b = *(const short8*)(sP + (j * 16 + l16) * 64 + k0);
            acc[j] = __builtin_amdgcn_mfma_f32_16x16x32_bf16(a, b, acc[j], 0, 0, 0);
        }
    }
    #pragma unroll
    for (int j = 0; j < 4; j++)
        #pragma unroll
        for (int r = 0; r < 4; r++)
            sT[(mrow + quad * 4 + r) * 64 + j * 16 + l16] = f2bf(acc[j][r]);  // sT = T1 [n][w]
    __syncthreads();

    // S2: T2[n][m] = sum_w T1[n][w] Wn[m][w];  A=sT rows, B reads sWn[m][w]
    #pragma unroll
    for (int j = 0; j < 4; j++) acc[j] = zero;
    #pragma unroll
    for (int ks = 0; ks < 2; ks++) {
        int k0 = ks * 32 + quad * 8;
        short8 a = *(const short8*)(sT + (mrow + l16) * 64 + k0);
        #pragma unroll
        for (int j = 0; j < 4; j++) {
            short8 b = *(const short8*)(sWn + (j * 16 + l16) * 64 + k0);
            acc[j] = __builtin_amdgcn_mfma_f32_16x16x32_bf16(a, b, acc[j], 0, 0, 0);
        }
    }
    __syncthreads();
    // epilogue: multiply Mod, store transposed into sP as [m][n]
    #pragma unroll
    for (int j = 0; j < 4; j++)
        #pragma unroll
        for (int r = 0; r < 4; r++) {
            int n = mrow + quad * 4 + r, m = j * 16 + l16;
            float v = acc[j][r] * bf2f(sM[n * 64 + m]);
            sP[m * 64 + n] = f2bf(v);
        }
    __syncthreads();

    // S3: T3[h][m] = sum_n WnT[h][n] T2'[n][m];  A=sWt rows, B reads sP[m][n]
    #pragma unroll
    for (int j = 0; j < 4; j++) acc[j] = zero;
    #pragma unroll
    for (int ks = 0; ks < 2; ks++) {
        int k0 = ks * 32 + quad * 8;
        short8 a = *(const short8*)(sWt + (mrow + l16) * 64 + k0);
        #pragma unroll
        for (int j = 0; j < 4; j++) {
            short8 b = *(const short8*)(sP + (j * 16 + l16) * 64 + k0);
            acc[j] = __builtin_amdgcn_mfma_f32_16x16x32_bf16(a, b, acc[j], 0, 0, 0);
        }
    }
    __syncthreads();
    #pragma unroll
    for (int j = 0; j < 4; j++)
        #pragma unroll
        for (int r = 0; r < 4; r++)
            sT[(mrow + quad * 4 + r) * 64 + j * 16 + l16] = f2bf(acc[j][r]);  // sT = T3 [h][m]
    __syncthreads();

    // S4: XO[h][w] = sum_m T3[h][m] Wn[m][w];  A=sT rows, B reads sWt[w][m]
    #pragma unroll
    for (int j = 0; j < 4; j++) acc[j] = zero;
    #pragma unroll
    for (int ks = 0; ks < 2; ks++) {
        int k0 = ks * 32 + quad * 8;
        short8 a = *(const short8*)(sT + (mrow + l16) * 64 + k0);
        #pragma unroll
        for (int j = 0; j < 4; j++) {
            short8 b = *(const short8*)(sWt + (j * 16 + l16) * 64 + k0);
            acc[j] = __builtin_amdgcn_mfma_f32_16x16x32_bf16(a, b, acc[j], 0, 0, 0);
        }
    }
    short* op = xo + (size_t)bc * 4096;
    #pragma unroll
    for (int j = 0; j < 4; j++)
        #pragma unroll
        for (int r = 0; r < 4; r++) {
            int h = mrow + quad * 4 + r, w = j * 16 + l16;
            op[h * 64 + w] = f2bf(acc[j][r]);
        }
}

// ---------------- layernorm over C, * silu(z) ----------------
__global__ __launch_bounds__(256) void k_ln_silu(const short* __restrict__ xo,  // [T][384]
                                                 const short* __restrict__ z,   // [T][384]
                                                 const float* __restrict__ g,
                                                 const float* __restrict__ bb,
                                                 short* __restrict__ y) {
    int wid = threadIdx.x >> 6, lane = threadIdx.x & 63;
    size_t token = (size_t)blockIdx.x * 4 + wid;
    const short* xp = xo + token * 384;
    float v[6];
    float s = 0.f, sq = 0.f;
    #pragma unroll
    for (int j = 0; j < 6; j++) {
        v[j] = bf2f(xp[lane + j * 64]);
        s += v[j]; sq += v[j] * v[j];
    }
    #pragma unroll
    for (int m = 1; m < 64; m <<= 1) {
        s  += __shfl_xor(s, m, 64);
        sq += __shfl_xor(sq, m, 64);
    }
    float mu = s * (1.0f / 384.0f);
    float var = sq * (1.0f / 384.0f) - mu * mu;
    float rstd = rsqrtf(var + 1e-5f);
    const short* zp = z + token * 384;
    short* yp = y + token * 384;
    #pragma unroll
    for (int j = 0; j < 6; j++) {
        int cc = lane + j * 64;
        float zz = bf2f(zp[cc]);
        float sil = zz / (1.f + __expf(-zz));
        float o = (v[j] - mu) * rstd * g[cc] + bb[cc];
        yp[cc] = f2bf(o * sil);
    }
}

// -------- GEMM3: out[M,384] = Y[M,384] * out_w^T + bias, fp32 store ---------
__global__ __launch_bounds__(256) void k_gemm_f32out(const short* __restrict__ A,
                                                     const short* __restrict__ Bw,
                                                     const float* __restrict__ bias,
                                                     float* __restrict__ D) {
    __shared__ __align__(16) short smem[17408];
    const int N = 384;
    int bid = blockIdx.x;
    int xcd = bid & 7, local = bid >> 3;
    int bx = local % 3;
    int by = xcd * 64 + local / 3;
    int row_base = by * 128, col_base = bx * 128;
    int tid = threadIdx.x;
    int wid = tid >> 6, lane = tid & 63, quad = lane >> 4, l16 = lane & 15;
    int rowh = (wid >> 1) * 64, colh = (wid & 1) * 64;

    floatx4 zero = {0.f, 0.f, 0.f, 0.f};
    floatx4 acc[4][4];
    #pragma unroll
    for (int i = 0; i < 4; i++)
        #pragma unroll
        for (int j = 0; j < 4; j++) acc[i][j] = zero;

    mm_core(A, Bw, row_base, col_base, smem, acc);

    #pragma unroll
    for (int i = 0; i < 4; i++) {
        #pragma unroll
        for (int j = 0; j < 4; j++) {
            int col = col_base + colh + j * 16 + l16;
            float bs = bias[col];
            #pragma unroll
            for (int r = 0; r < 4; r++) {
                int row = row_base + rowh + i * 16 + quad * 4 + r;
                D[(size_t)row * N + col] = acc[i][j][r] + bs;
            }
        }
    }
}

// ---------------------------------------------------------------------------
extern "C" void kernel_launch(void* const* d_in, const int* in_sizes, int n_in,
                              void* d_out, int out_size, void* d_ws, size_t ws_size,
                              hipStream_t stream) {
    const float* x     = (const float*)d_in[0];
    const float* freq  = (const float*)d_in[1];
    const float* dw_w  = (const float*)d_in[2];
    const float* dw_b  = (const float*)d_in[3];
    const float* lin_w = (const float*)d_in[4];
    const float* lin_b = (const float*)d_in[5];
    const float* tok_w = (const float*)d_in[6];
    const float* tok_b = (const float*)d_in[7];
    const float* ln_g  = (const float*)d_in[8];
    const float* ln_b  = (const float*)d_in[9];
    const float* out_w = (const float*)d_in[10];
    const float* out_b = (const float*)d_in[11];
    const float* cp    = (const float*)d_in[12];
    const float* ap    = (const float*)d_in[13];
    float* out = (float*)d_out;
    (void)in_sizes; (void)n_in; (void)ws_size;

    // d_out (96MiB fp32) doubles as two 48MiB bf16 scratch tensors until GEMM3.
    const size_t TC = (size_t)65536 * 384;   // 25165824
    short* bufA = (short*)d_out;             // xs plane -> xo token
    short* bufB = (short*)d_out + TC;        // z token (alive until ln_silu)

    char* ws = (char*)d_ws;
    size_t off = 0;
    auto alloc = [&](size_t bytes) {
        char* p = ws + off; off += (bytes + 255) & ~(size_t)255; return p;
    };
    short* wn_bf   = (short*)alloc(4096 * 2);
    short* wnt_bf  = (short*)alloc(4096 * 2);
    short* linw_bf = (short*)alloc((size_t)294912 * 2);
    short* tokw_bf = (short*)alloc((size_t)147456 * 2);
    short* outw_bf = (short*)alloc((size_t)147456 * 2);
    short* bufC    = (short*)alloc(TC * 2);  // xd token -> mod plane -> y token
    short* bufE    = (short*)alloc(TC * 2);  // xd plane -> freq bf16 -> xo plane
    // total ws: ~98.3 MB

    k_f2bf<<<288, 256, 0, stream>>>(lin_w, linw_bf, 294912);
    k_f2bf<<<144, 256, 0, stream>>>(tok_w, tokw_bf, 147456);
    k_f2bf<<<144, 256, 0, stream>>>(out_w, outw_bf, 147456);
    k_build_dct<<<16, 256, 0, stream>>>(wn_bf, wnt_bf);

    k_conv<<<6144, 256, 0, stream>>>(x, dw_w, dw_b, bufE);            // xd plane
    k_pl2tok<<<dim3(6, 64, 16), 256, 0, stream>>>(bufE, bufC);        // xd token
    k_gemm_split<<<3072, 256, 0, stream>>>(bufC, linw_bf, lin_b,
                                           bufA, bufB);               // xs PLANE, z token
    k_f2bf<<<24576, 256, 0, stream>>>(freq, bufE, 25165824);          // freq bf16 (xd plane dead)
    k_gemm_mod<<<1536, 256, 0, stream>>>(bufE, tokw_bf, tok_b,
                                         bufC, cp, ap);               // mod plane (xd tok dead)
    k_spectral<<<6144, 256, 0, stream>>>(bufA, bufC, wn_bf, wnt_bf,
                                         bufE);                       // xo plane (freq bf dead)
    k_pl2tok<<<dim3(6, 64, 16), 256, 0, stream>>>(bufE, bufA);        // xo token (xs plane dead)
    k_ln_silu<<<16384, 256, 0, stream>>>(bufA, bufB, ln_g, ln_b, bufC); // y token (mod dead)
    k_gemm_f32out<<<1536, 256, 0, stream>>>(bufC, outw_bf, out_b, out);
}